// Round 10
// baseline (327.322 us; speedup 1.0000x reference)
//
#include <hip/hip_runtime.h>
#include <hip/hip_fp16.h>
#include <cstdint>

#define NN 100000
#define NE 1600000
#define INDIM 165
#define HID 64
#define KP1 192   // INDIM padded to 6*32
#define KP2 64

// dst-bucket partition: bucket = dst >> BSH, BNODES nodes per bucket
constexpr int BSH = 7;
constexpr int BNODES = 128;               // 1 << BSH
constexpr int NBUK = (NN + BNODES - 1) / BNODES; // 782
constexpr int SC_CHUNK = 8192;            // edges per scatter block
// fixed-capacity bucket store: E[bucket] ~ Binomial(1.6M, 1/782), mean 2046,
// sigma ~45 -> 2816 is ~17 sigma. Zero-based cursor reservation (no bhist).
constexpr int BCAP = 2816;

typedef _Float16 f16x8 __attribute__((ext_vector_type(8)));
typedef _Float16 h2 __attribute__((ext_vector_type(2)));
typedef float f32x4 __attribute__((ext_vector_type(4)));

// ---------------- scan of 782 bucket counts (single block) ----------------

__global__ __launch_bounds__(256) void k_bscan(const int* __restrict__ bcnt,
                                               int* __restrict__ bbase) {
    __shared__ int wsum[4];
    const int tid = threadIdx.x, lane = tid & 63, wid = tid >> 6;
    int v[4];
    int tsum = 0;
#pragma unroll
    for (int i = 0; i < 4; ++i) {
        int idx = tid * 4 + i;
        v[i] = (idx < NBUK) ? bcnt[idx] : 0;
        tsum += v[i];
    }
    int x = tsum;
#pragma unroll
    for (int off = 1; off < 64; off <<= 1) {
        int y = __shfl_up(x, off, 64);
        if (lane >= off) x += y;
    }
    if (lane == 63) wsum[wid] = x;
    __syncthreads();
    int woff = 0;
#pragma unroll
    for (int w = 0; w < 4; ++w)
        if (w < wid) woff += wsum[w];
    int run = woff + x - tsum;
#pragma unroll
    for (int i = 0; i < 4; ++i) {
        int idx = tid * 4 + i;
        if (idx < NBUK) bbase[idx] = run;
        run += v[i];
    }
    if (tid == 255) bbase[NBUK] = woff + x; // grand total (= ne)
}

// ---------------- single-pass partition into fixed-capacity buckets -------
// Packed entry: src (17b, NN<2^17) | node-in-bucket (7b) << 17.

__global__ __launch_bounds__(256) void k_scatter(const int* __restrict__ src,
                                                 const int* __restrict__ dst,
                                                 int* __restrict__ bcnt,
                                                 unsigned* __restrict__ Eb, int ne) {
    __shared__ int hist[NBUK];
    __shared__ int base[NBUK];
    const int tid = threadIdx.x;
    const int cs = blockIdx.x * SC_CHUNK;
    for (int b = tid; b < NBUK; b += 256) hist[b] = 0;
    __syncthreads();
    unsigned pack[SC_CHUNK / 256];
#pragma unroll 8
    for (int i = 0; i < SC_CHUNK / 256; ++i) {
        int e = cs + i * 256 + tid;
        if (e < ne) {
            int b = dst[e] >> BSH;
            int r = atomicAdd(&hist[b], 1);      // rank within (block,bucket)
            pack[i] = (unsigned)((b << 13) | r); // b<=781 (10b), r<8192 (13b)
        } else {
            pack[i] = 0xFFFFFFFFu;
        }
    }
    __syncthreads();
    for (int b = tid; b < NBUK; b += 256) {
        int c = hist[b];
        base[b] = c ? atomicAdd(&bcnt[b], c) : 0; // zero-based reservation
    }
    __syncthreads();
#pragma unroll 8
    for (int i = 0; i < SC_CHUNK / 256; ++i) {
        if (pack[i] != 0xFFFFFFFFu) {
            int e = cs + i * 256 + tid;
            int b = pack[i] >> 13, r = pack[i] & 8191;
            int pos = base[b] + r;
            if (pos < BCAP)                      // never triggers (17 sigma)
                Eb[(size_t)b * BCAP + pos] =
                    (unsigned)src[e] | ((unsigned)(dst[e] & (BNODES - 1)) << 17);
        }
    }
}

// ---------------- per-bucket CSR build (packed Eb input) ------------------
// r16 lesson: LDS fp32 atomicAdd is a CAS loop on AMD -> 13x slower. CSR stays.

__global__ __launch_bounds__(256) void k_csrb(const unsigned* __restrict__ Eb,
                                              const int* __restrict__ bbase,
                                              int* __restrict__ rowptr,
                                              int* __restrict__ col, int n) {
    __shared__ int cnt[BNODES];
    __shared__ int pref[BNODES];
    const int tid = threadIdx.x;
    const int gb = bbase[blockIdx.x];
    const int m = bbase[blockIdx.x + 1] - gb;
    const unsigned* eb = Eb + (size_t)blockIdx.x * BCAP;
    for (int i = tid; i < BNODES; i += 256) cnt[i] = 0;
    __syncthreads();
    for (int e = tid; e < m; e += 256)
        atomicAdd(&cnt[eb[e] >> 17], 1);
    __syncthreads();
    if (tid < 64) { // wave 0 scans 128 counts, 2/lane (wave-uniform branch)
        int c0 = cnt[tid * 2], c1 = cnt[tid * 2 + 1];
        int s = c0 + c1;
        int x = s;
#pragma unroll
        for (int off = 1; off < 64; off <<= 1) {
            int y = __shfl_up(x, off, 64);
            if (tid >= off) x += y;
        }
        int ex = x - s; // exclusive
        pref[tid * 2] = ex;
        pref[tid * 2 + 1] = ex + c0;
    }
    __syncthreads();
    const int nodeBase = blockIdx.x * BNODES;
    for (int i = tid; i < BNODES; i += 256) {
        int gn = nodeBase + i;
        if (gn < n) rowptr[gn] = gb + pref[i];
        cnt[i] = 0; // reuse as cursor
    }
    __syncthreads();
    for (int e = tid; e < m; e += 256) {
        unsigned v = eb[e];
        int d = (int)(v >> 17);
        int r = atomicAdd(&cnt[d], 1);
        col[gb + pref[d] + r] = (int)(v & 0x1FFFFu);
    }
    if (blockIdx.x == 0 && tid == 0) rowptr[n] = bbase[NBUK];
}

// ---------------- one-time weight convert -----------------------------

__global__ __launch_bounds__(256) void k_wcvt(const float* __restrict__ W1l,
                                              const float* __restrict__ W1r,
                                              const float* __restrict__ W2l,
                                              const float* __restrict__ W2r,
                                              _Float16* __restrict__ Wt1,
                                              _Float16* __restrict__ Wt2) {
    int o = blockIdx.x * 256 + threadIdx.x;
    if (o < 128 * KP1) {
        int c = o / KP1, k = o - c * KP1;
        float v = 0.f;
        if (k < INDIM) v = (c < HID) ? W1l[k * HID + c] : W1r[k * HID + (c - HID)];
        Wt1[o] = (_Float16)v;
    } else if (o < 128 * KP1 + 128 * KP2) {
        int p = o - 128 * KP1;
        int c = p / KP2, k = p - c * KP2;
        float v = (c < HID) ? W2l[k * HID + c] : W2r[k * HID + (c - HID)];
        Wt2[p] = (_Float16)v;
    }
}

// ---------------- layer-1 dual linear: fp32 X, LDS-staged -----------------
// r19 post-mortem of r18 (60us, VALU 7.4%, HBM 12%): staging was coalesced
// but SERIALIZED — 41 scalar-dword iterations each with a load->cvt->
// ds_write dependency, so ~1 load in flight per wave. Fix: float4 loads
// (16B/lane = 1KB/wave-instr) BATCHED 4-deep into registers before any LDS
// write -> 4x16B in flight, ~11 loads in 3 batches per thread. Row/col
// decode per element is cheap (VALU idle). vr*165 % 4 == 0 for both block
// shapes (vr = 64 or 32 at NN=100000).

__global__ __launch_bounds__(256, 4) void k_lin1(const float* __restrict__ X,
                                                 const _Float16* __restrict__ Wt,
                                                 _Float16* __restrict__ Y,
                                                 _Float16* __restrict__ Rh, int n) {
    constexpr int LDK = 200; // halves/row: 400B stride, 16B-aligned, 2-way banks
    __shared__ _Float16 Xs[64][LDK];
    const int tid = threadIdx.x;
    const int lane = tid & 63;
    const int w = tid >> 6;      // wave id: owns nodes w*16 .. w*16+15
    const int jn = lane & 15;    // node-within-wave / W-row-within-tile
    const int kq = lane >> 4;    // k-quad: fragment k = kq*8 .. kq*8+7
    const int r0 = blockIdx.x * 64;

    // zero LDS (covers k>=165 pad and invalid tail rows)
    for (int i = tid; i < 64 * LDK / 8; i += 256)
        ((f16x8*)&Xs[0][0])[i] = (f16x8)(_Float16)0.f;
    __syncthreads();

    const int vr = (n - r0 < 64) ? (n - r0) : 64;   // valid rows this block
    const int nq = (vr * INDIM) >> 2;               // float4 count (divisible)
    const float4* __restrict__ P4 = (const float4*)(X + (size_t)r0 * INDIM);
    for (int i0 = tid; i0 < nq; i0 += 1024) {       // 4 float4 in flight/thread
        float4 v[4];
        int ok[4];
#pragma unroll
        for (int j = 0; j < 4; ++j) {
            const int idx = i0 + j * 256;
            ok[j] = idx < nq;
            v[j] = ok[j] ? P4[idx] : make_float4(0.f, 0.f, 0.f, 0.f);
        }
#pragma unroll
        for (int j = 0; j < 4; ++j) {
            if (ok[j]) {
                const int e = (i0 + j * 256) * 4;
                const float va[4] = {v[j].x, v[j].y, v[j].z, v[j].w};
#pragma unroll
                for (int q = 0; q < 4; ++q) {
                    const int ee = e + q;
                    const int row = ee / INDIM;      // magic-mul const div
                    const int kcol = ee - row * INDIM;
                    Xs[row][kcol] = (_Float16)va[q];
                }
            }
        }
    }
    __syncthreads();

    const _Float16* wp = Wt + (size_t)jn * KP1 + kq * 8;
    const _Float16* xs = &Xs[w * 16 + jn][kq * 8];

    f32x4 acc[8];
#pragma unroll
    for (int t = 0; t < 8; ++t) acc[t] = (f32x4){0.f, 0.f, 0.f, 0.f};

#pragma unroll
    for (int c = 0; c < 6; ++c) {
        const f16x8 xb = *(const f16x8*)(xs + c * 32);
#pragma unroll
        for (int t = 0; t < 8; ++t) {               // A' frag: W^T[col][k]
            const f16x8 wa = *(const f16x8*)(wp + t * (16 * KP1) + c * 32);
            acc[t] = __builtin_amdgcn_mfma_f32_16x16x32_f16(wa, xb, acc[t], 0, 0, 0);
        }
    }

    const int gn0 = r0 + w * 16 + jn;
    if (gn0 < n) {
#pragma unroll
        for (int t = 0; t < 8; ++t) {
            const int cb = (t & 3) * 16 + kq * 4;
            union { _Float16 h[4]; uint2 u; } u;
#pragma unroll
            for (int r = 0; r < 4; ++r) u.h[r] = (_Float16)acc[t][r];
            _Float16* dstp = (t < 4) ? (Y + (size_t)gn0 * HID + cb)
                                     : (Rh + (size_t)gn0 * HID + cb);
            *(uint2*)dstp = u.u;
        }
    }
}

// ---------------- layer-2 dual linear (fp16 in, unchanged) ----------------

template <int KPAD>
__global__ __launch_bounds__(256, 4) void k_linear(const _Float16* __restrict__ Xh,
                                                   const _Float16* __restrict__ Wt,
                                                   _Float16* __restrict__ Y,
                                                   _Float16* __restrict__ Rh, int n) {
    const int tid = threadIdx.x;
    const int lane = tid & 63;
    const int w = tid >> 6;
    const int jn = lane & 15;
    const int kq = lane >> 4;
    const int gn0 = blockIdx.x * 64 + w * 16 + jn;
    const int gn = (gn0 < n) ? gn0 : (n - 1);

    const _Float16* xp = Xh + (size_t)gn * KPAD + kq * 8;
    const _Float16* wp = Wt + (size_t)jn * KPAD + kq * 8;

    f16x8 xf[KPAD / 32];
#pragma unroll
    for (int c = 0; c < KPAD / 32; ++c)
        xf[c] = *(const f16x8*)(xp + c * 32);

    f32x4 acc[8];
#pragma unroll
    for (int t = 0; t < 8; ++t) acc[t] = (f32x4){0.f, 0.f, 0.f, 0.f};

#pragma unroll
    for (int c = 0; c < KPAD / 32; ++c) {
#pragma unroll
        for (int t = 0; t < 8; ++t) {
            const f16x8 wa = *(const f16x8*)(wp + t * (16 * KPAD) + c * 32);
            acc[t] = __builtin_amdgcn_mfma_f32_16x16x32_f16(wa, xf[c], acc[t], 0, 0, 0);
        }
    }

    if (gn0 < n) {
#pragma unroll
        for (int t = 0; t < 8; ++t) {
            const int cb = (t & 3) * 16 + kq * 4;
            union { _Float16 h[4]; uint2 u; } u;
#pragma unroll
            for (int r = 0; r < 4; ++r) u.h[r] = (_Float16)acc[t][r];
            _Float16* dstp = (t < 4) ? (Y + (size_t)gn * HID + cb)
                                     : (Rh + (size_t)gn * HID + cb);
            *(uint2*)dstp = u.u;
        }
    }
}

// ---------------- aggregation (+ optional fused classifier) ----------------
// Half-wave h2 gathers, 16-edge batches, fp32 accumulate (measured-best form).

__device__ __forceinline__ void acc2(float& ax, float& ay, h2 v) {
    ax += (float)v[0];
    ay += (float)v[1];
}

template <bool CLS>
__global__ __launch_bounds__(256) void k_agg(const _Float16* __restrict__ Y,
                                             const _Float16* __restrict__ Rm,
                                             const float* __restrict__ bias,
                                             const int* __restrict__ rowptr,
                                             const int* __restrict__ col,
                                             _Float16* __restrict__ H,
                                             const float* __restrict__ Wc,
                                             const float* __restrict__ bc,
                                             float* __restrict__ out, int n) {
    const int lane = threadIdx.x & 63;
    const int node = blockIdx.x * 4 + (threadIdx.x >> 6);
    if (node >= n) return;
    const int half_ = lane >> 5;            // which edge of the pair
    const unsigned fp = (unsigned)(lane & 31); // feature-pair index (h2 units)
    const h2* __restrict__ Y2 = (const h2*)Y;
    const int s = rowptr[node], e = rowptr[node + 1];
    float ax0 = 0.f, ay0 = 0.f, ax1 = 0.f, ay1 = 0.f;
    int i = s + half_;
    for (; i + 14 < e; i += 16) {           // 8 edges per half-wave in flight
        int c[8];
#pragma unroll
        for (int j = 0; j < 8; ++j) c[j] = col[i + 2 * j];
        h2 y[8];
#pragma unroll
        for (int j = 0; j < 8; ++j) y[j] = Y2[(unsigned)c[j] * 32u + fp];
#pragma unroll
        for (int j = 0; j < 8; j += 2) {
            acc2(ax0, ay0, y[j]);
            acc2(ax1, ay1, y[j + 1]);
        }
    }
    for (; i + 6 < e; i += 8) {
        int c[4];
#pragma unroll
        for (int j = 0; j < 4; ++j) c[j] = col[i + 2 * j];
        h2 y[4];
#pragma unroll
        for (int j = 0; j < 4; ++j) y[j] = Y2[(unsigned)c[j] * 32u + fp];
        acc2(ax0, ay0, y[0]);
        acc2(ax1, ay1, y[1]);
        acc2(ax0, ay0, y[2]);
        acc2(ax1, ay1, y[3]);
    }
    for (; i < e; i += 2)
        acc2(ax0, ay0, Y2[(unsigned)col[i] * 32u + fp]);
    float ax = ax0 + ax1, ay = ay0 + ay1;
    ax += __shfl_xor(ax, 32, 64);
    ay += __shfl_xor(ay, 32, 64);
    const float vx = __shfl(ax, lane >> 1, 64);
    const float vy = __shfl(ay, lane >> 1, 64);
    const float acc = (lane & 1) ? vy : vx;
    const int deg = e - s;
    float h = acc / (float)(deg > 1 ? deg : 1) + bias[lane] +
              (float)Rm[(size_t)node * HID + lane];
    h = fmaxf(h, 0.f);
    if (!CLS) {
        H[(size_t)node * HID + lane] = (_Float16)h;
    } else {
        float p0 = h * Wc[lane * 2 + 0];
        float p1 = h * Wc[lane * 2 + 1];
#pragma unroll
        for (int off = 32; off > 0; off >>= 1) {
            p0 += __shfl_xor(p0, off, 64);
            p1 += __shfl_xor(p1, off, 64);
        }
        if (lane == 0) {
            out[(size_t)node * 2 + 0] = p0 + bc[0];
            out[(size_t)node * 2 + 1] = p1 + bc[1];
        }
    }
}

// ---------------- launch ----------------

extern "C" void kernel_launch(void* const* d_in, const int* in_sizes, int n_in,
                              void* d_out, int out_size, void* d_ws, size_t ws_size,
                              hipStream_t stream) {
    const float* x   = (const float*)d_in[0];
    const int*   ei  = (const int*)d_in[1];
    const float* W1l = (const float*)d_in[2];
    const float* b1  = (const float*)d_in[3];
    const float* W1r = (const float*)d_in[4];
    const float* W2l = (const float*)d_in[5];
    const float* b2  = (const float*)d_in[6];
    const float* W2r = (const float*)d_in[7];
    const float* Wc  = (const float*)d_in[8];
    const float* bc  = (const float*)d_in[9];
    float* out = (float*)d_out;
    const int* src = ei;
    const int* dst = ei + NE;

    char* base = (char*)d_ws;
    size_t off = 0;
    auto alloc = [&](size_t bytes) {
        void* p = base + off;
        off = (off + bytes + 255) & ~(size_t)255;
        return p;
    };
    int*      bcnt    = (int*)alloc((size_t)NBUK * 4);
    int*      bbase   = (int*)alloc((size_t)(NBUK + 1) * 4);
    int*      rowptr  = (int*)alloc((size_t)(NN + 1) * 4);
    int*      col     = (int*)alloc((size_t)NE * 4);
    // Eb (8.8 MB) is dead after k_csrb -> alias it under Y (fp16, 12.8 MB)
    _Float16* Y       = (_Float16*)alloc((size_t)NN * HID * 2 + 256);
    _Float16* Rh      = (_Float16*)alloc((size_t)NN * HID * 2);
    _Float16* Hh      = (_Float16*)alloc((size_t)NN * HID * 2);
    _Float16* Wt1     = (_Float16*)alloc((size_t)128 * KP1 * 2);
    _Float16* Wt2     = (_Float16*)alloc((size_t)128 * KP2 * 2);
    unsigned* Eb      = (unsigned*)Y;

    const int sb = (NE + SC_CHUNK - 1) / SC_CHUNK; // 196
    const int wb = (128 * KP1 + 128 * KP2 + 255) / 256; // 128

    hipMemsetAsync(bcnt, 0, (size_t)NBUK * 4, stream);
    k_scatter<<<sb, 256, 0, stream>>>(src, dst, bcnt, Eb, NE);
    k_bscan<<<1, 256, 0, stream>>>(bcnt, bbase);
    k_csrb<<<NBUK, 256, 0, stream>>>(Eb, bbase, rowptr, col, NN);
    k_wcvt<<<wb, 256, 0, stream>>>(W1l, W1r, W2l, W2r, Wt1, Wt2);

    k_lin1<<<(NN + 63) / 64, 256, 0, stream>>>(x, Wt1, Y, Rh, NN);
    k_agg<false><<<(NN + 3) / 4, 256, 0, stream>>>(Y, Rh, b1, rowptr, col, Hh,
                                                   nullptr, nullptr, nullptr, NN);
    k_linear<KP2><<<(NN + 63) / 64, 256, 0, stream>>>(Hh, Wt2, Y, Rh, NN);
    k_agg<true><<<(NN + 3) / 4, 256, 0, stream>>>(Y, Rh, b2, rowptr, col, nullptr,
                                                  Wc, bc, out, NN);
}

// Round 11
// 324.677 us; speedup vs baseline: 1.0081x; 1.0081x over previous
//
#include <hip/hip_runtime.h>
#include <hip/hip_fp16.h>
#include <cstdint>

#define NN 100000
#define NE 1600000
#define INDIM 165
#define HID 64
#define KP1 192   // INDIM padded to 6*32
#define KP2 64

// dst-bucket partition: bucket = dst >> BSH, BNODES nodes per bucket
constexpr int BSH = 7;
constexpr int BNODES = 128;               // 1 << BSH
constexpr int NBUK = (NN + BNODES - 1) / BNODES; // 782
constexpr int SC_CHUNK = 8192;            // edges per scatter block
// fixed-capacity bucket store: E[bucket] ~ Binomial(1.6M, 1/782), mean 2046,
// sigma ~45 -> 2816 is ~17 sigma. Zero-based cursor reservation (no bhist).
constexpr int BCAP = 2816;

typedef _Float16 f16x8 __attribute__((ext_vector_type(8)));
typedef _Float16 h2 __attribute__((ext_vector_type(2)));
typedef float f32x4 __attribute__((ext_vector_type(4)));

// async HBM->LDS, 16B per lane per instruction. Global addr is PER-LANE,
// LDS dest is wave-uniform base + lane*16 (m104/m108).
__device__ __forceinline__ void gload16(const float* g, float* l) {
    __builtin_amdgcn_global_load_lds(
        (const __attribute__((address_space(1))) uint32_t*)g,
        (__attribute__((address_space(3))) uint32_t*)l, 16, 0, 0);
}

// ---------------- scan of 782 bucket counts (single block) ----------------

__global__ __launch_bounds__(256) void k_bscan(const int* __restrict__ bcnt,
                                               int* __restrict__ bbase) {
    __shared__ int wsum[4];
    const int tid = threadIdx.x, lane = tid & 63, wid = tid >> 6;
    int v[4];
    int tsum = 0;
#pragma unroll
    for (int i = 0; i < 4; ++i) {
        int idx = tid * 4 + i;
        v[i] = (idx < NBUK) ? bcnt[idx] : 0;
        tsum += v[i];
    }
    int x = tsum;
#pragma unroll
    for (int off = 1; off < 64; off <<= 1) {
        int y = __shfl_up(x, off, 64);
        if (lane >= off) x += y;
    }
    if (lane == 63) wsum[wid] = x;
    __syncthreads();
    int woff = 0;
#pragma unroll
    for (int w = 0; w < 4; ++w)
        if (w < wid) woff += wsum[w];
    int run = woff + x - tsum;
#pragma unroll
    for (int i = 0; i < 4; ++i) {
        int idx = tid * 4 + i;
        if (idx < NBUK) bbase[idx] = run;
        run += v[i];
    }
    if (tid == 255) bbase[NBUK] = woff + x; // grand total (= ne)
}

// ---------------- single-pass partition into fixed-capacity buckets -------
// Packed entry: src (17b, NN<2^17) | node-in-bucket (7b) << 17.

__global__ __launch_bounds__(256) void k_scatter(const int* __restrict__ src,
                                                 const int* __restrict__ dst,
                                                 int* __restrict__ bcnt,
                                                 unsigned* __restrict__ Eb, int ne) {
    __shared__ int hist[NBUK];
    __shared__ int base[NBUK];
    const int tid = threadIdx.x;
    const int cs = blockIdx.x * SC_CHUNK;
    for (int b = tid; b < NBUK; b += 256) hist[b] = 0;
    __syncthreads();
    unsigned pack[SC_CHUNK / 256];
#pragma unroll 8
    for (int i = 0; i < SC_CHUNK / 256; ++i) {
        int e = cs + i * 256 + tid;
        if (e < ne) {
            int b = dst[e] >> BSH;
            int r = atomicAdd(&hist[b], 1);      // rank within (block,bucket)
            pack[i] = (unsigned)((b << 13) | r); // b<=781 (10b), r<8192 (13b)
        } else {
            pack[i] = 0xFFFFFFFFu;
        }
    }
    __syncthreads();
    for (int b = tid; b < NBUK; b += 256) {
        int c = hist[b];
        base[b] = c ? atomicAdd(&bcnt[b], c) : 0; // zero-based reservation
    }
    __syncthreads();
#pragma unroll 8
    for (int i = 0; i < SC_CHUNK / 256; ++i) {
        if (pack[i] != 0xFFFFFFFFu) {
            int e = cs + i * 256 + tid;
            int b = pack[i] >> 13, r = pack[i] & 8191;
            int pos = base[b] + r;
            if (pos < BCAP)                      // never triggers (17 sigma)
                Eb[(size_t)b * BCAP + pos] =
                    (unsigned)src[e] | ((unsigned)(dst[e] & (BNODES - 1)) << 17);
        }
    }
}

// ---------------- per-bucket CSR build (packed Eb input) ------------------
// r16 lesson: LDS fp32 atomicAdd is a CAS loop on AMD -> 13x slower. CSR stays.

__global__ __launch_bounds__(256) void k_csrb(const unsigned* __restrict__ Eb,
                                              const int* __restrict__ bbase,
                                              int* __restrict__ rowptr,
                                              int* __restrict__ col, int n) {
    __shared__ int cnt[BNODES];
    __shared__ int pref[BNODES];
    const int tid = threadIdx.x;
    const int gb = bbase[blockIdx.x];
    const int m = bbase[blockIdx.x + 1] - gb;
    const unsigned* eb = Eb + (size_t)blockIdx.x * BCAP;
    for (int i = tid; i < BNODES; i += 256) cnt[i] = 0;
    __syncthreads();
    for (int e = tid; e < m; e += 256)
        atomicAdd(&cnt[eb[e] >> 17], 1);
    __syncthreads();
    if (tid < 64) { // wave 0 scans 128 counts, 2/lane (wave-uniform branch)
        int c0 = cnt[tid * 2], c1 = cnt[tid * 2 + 1];
        int s = c0 + c1;
        int x = s;
#pragma unroll
        for (int off = 1; off < 64; off <<= 1) {
            int y = __shfl_up(x, off, 64);
            if (tid >= off) x += y;
        }
        int ex = x - s; // exclusive
        pref[tid * 2] = ex;
        pref[tid * 2 + 1] = ex + c0;
    }
    __syncthreads();
    const int nodeBase = blockIdx.x * BNODES;
    for (int i = tid; i < BNODES; i += 256) {
        int gn = nodeBase + i;
        if (gn < n) rowptr[gn] = gb + pref[i];
        cnt[i] = 0; // reuse as cursor
    }
    __syncthreads();
    for (int e = tid; e < m; e += 256) {
        unsigned v = eb[e];
        int d = (int)(v >> 17);
        int r = atomicAdd(&cnt[d], 1);
        col[gb + pref[d] + r] = (int)(v & 0x1FFFFu);
    }
    if (blockIdx.x == 0 && tid == 0) rowptr[n] = bbase[NBUK];
}

// ---------------- one-time weight convert -----------------------------

__global__ __launch_bounds__(256) void k_wcvt(const float* __restrict__ W1l,
                                              const float* __restrict__ W1r,
                                              const float* __restrict__ W2l,
                                              const float* __restrict__ W2r,
                                              _Float16* __restrict__ Wt1,
                                              _Float16* __restrict__ Wt2) {
    int o = blockIdx.x * 256 + threadIdx.x;
    if (o < 128 * KP1) {
        int c = o / KP1, k = o - c * KP1;
        float v = 0.f;
        if (k < INDIM) v = (c < HID) ? W1l[k * HID + c] : W1r[k * HID + (c - HID)];
        Wt1[o] = (_Float16)v;
    } else if (o < 128 * KP1 + 128 * KP2) {
        int p = o - 128 * KP1;
        int c = p / KP2, k = p - c * KP2;
        float v = (c < HID) ? W2l[k * HID + c] : W2r[k * HID + (c - HID)];
        Wt2[p] = (_Float16)v;
    }
}

// ---------------- layer-1 dual linear: async-staged fp32 X ---------------
// r20 post-mortem of r17/r18/r19 (all 60-66us, every pipe idle): ANY
// register-staged staging serializes — load must return to VGPR, cvt,
// ds_write, barrier; ~22KB/CU in flight caps HBM at ~900 GB/s. Fix per
// Common-mistake #1: __builtin_amdgcn_global_load_lds width=16 — each wave
// fires ~10 async 1KB HBM->LDS DMAs (no VGPR trip, no dep chain), ONE
// barrier drains vmcnt. LDS layout must be LINEAR (wave-uniform base +
// lane*16): fp32 [64][165] unpadded; convert on fragment read (8x
// ds_read_b32, banks (5*jn+8*kq)%32 = 2-way = free). nFull full DMAs +
// <=255-dword tail via regular loads (no global OOB); 192-dword zero-guard
// past the slab keeps the last row's chunk-5 overhang finite (x * Wpad=0).

__global__ __launch_bounds__(256) void k_lin1(const float* __restrict__ X,
                                              const _Float16* __restrict__ Wt,
                                              _Float16* __restrict__ Y,
                                              _Float16* __restrict__ Rh, int n) {
    constexpr int ROWD = INDIM;         // dwords per row (no pad: linear dest)
    constexpr int LDSZ = 64 * 168;      // 10752 dwords = 43008 B
    __shared__ float Xs[LDSZ];
    const int tid = threadIdx.x;
    const int lane = tid & 63;
    const int wi = tid >> 6;            // wave id: owns nodes wi*16..wi*16+15
    const int jn = lane & 15;           // node-within-wave / W-row-in-tile
    const int kq = lane >> 4;           // k-quad: fragment k = kq*8..kq*8+7
    const int r0 = blockIdx.x * 64;
    const int vr = (n - r0 < 64) ? (n - r0) : 64;
    const int cnt = vr * ROWD;          // slab dwords (10560 or 5280)
    const int nFull = cnt >> 8;         // full 1024B DMA instructions
    const float* __restrict__ P = X + (size_t)r0 * ROWD;

    // NaN-guard: zero 192 dwords just past the slab (fragment overhang zone)
    for (int i = cnt + tid; i < cnt + 192 && i < LDSZ; i += 256) Xs[i] = 0.f;

    // async DMA: wave wi stages instrs wi, wi+4, ... (disjoint LDS regions)
    for (int i = wi; i < nFull; i += 4)
        gload16(P + i * 256 + lane * 4, Xs + i * 256);
    // tail dwords (cnt % 256) via regular loads
    for (int i = (nFull << 8) + tid; i < cnt; i += 256) Xs[i] = P[i];
    __syncthreads();                    // drains vmcnt + lgkmcnt

    const _Float16* wp = Wt + (size_t)jn * KP1 + kq * 8;
    const float* xrow = &Xs[(wi * 16 + jn) * ROWD + kq * 8];

    f32x4 acc[8];
#pragma unroll
    for (int t = 0; t < 8; ++t) acc[t] = (f32x4){0.f, 0.f, 0.f, 0.f};

#pragma unroll
    for (int c = 0; c < 6; ++c) {
        f16x8 xb;
#pragma unroll
        for (int j = 0; j < 8; ++j) xb[j] = (_Float16)xrow[c * 32 + j];
#pragma unroll
        for (int t = 0; t < 8; ++t) {               // A' frag: W^T[col][k]
            const f16x8 wa = *(const f16x8*)(wp + t * (16 * KP1) + c * 32);
            acc[t] = __builtin_amdgcn_mfma_f32_16x16x32_f16(wa, xb, acc[t], 0, 0, 0);
        }
    }

    const int gn0 = r0 + wi * 16 + jn;
    if (gn0 < n) {
#pragma unroll
        for (int t = 0; t < 8; ++t) {
            const int cb = (t & 3) * 16 + kq * 4;
            union { _Float16 h[4]; uint2 u; } u;
#pragma unroll
            for (int r = 0; r < 4; ++r) u.h[r] = (_Float16)acc[t][r];
            _Float16* dstp = (t < 4) ? (Y + (size_t)gn0 * HID + cb)
                                     : (Rh + (size_t)gn0 * HID + cb);
            *(uint2*)dstp = u.u;
        }
    }
}

// ---------------- layer-2 dual linear (fp16 in, unchanged) ----------------

template <int KPAD>
__global__ __launch_bounds__(256, 4) void k_linear(const _Float16* __restrict__ Xh,
                                                   const _Float16* __restrict__ Wt,
                                                   _Float16* __restrict__ Y,
                                                   _Float16* __restrict__ Rh, int n) {
    const int tid = threadIdx.x;
    const int lane = tid & 63;
    const int w = tid >> 6;
    const int jn = lane & 15;
    const int kq = lane >> 4;
    const int gn0 = blockIdx.x * 64 + w * 16 + jn;
    const int gn = (gn0 < n) ? gn0 : (n - 1);

    const _Float16* xp = Xh + (size_t)gn * KPAD + kq * 8;
    const _Float16* wp = Wt + (size_t)jn * KPAD + kq * 8;

    f16x8 xf[KPAD / 32];
#pragma unroll
    for (int c = 0; c < KPAD / 32; ++c)
        xf[c] = *(const f16x8*)(xp + c * 32);

    f32x4 acc[8];
#pragma unroll
    for (int t = 0; t < 8; ++t) acc[t] = (f32x4){0.f, 0.f, 0.f, 0.f};

#pragma unroll
    for (int c = 0; c < KPAD / 32; ++c) {
#pragma unroll
        for (int t = 0; t < 8; ++t) {
            const f16x8 wa = *(const f16x8*)(wp + t * (16 * KPAD) + c * 32);
            acc[t] = __builtin_amdgcn_mfma_f32_16x16x32_f16(wa, xf[c], acc[t], 0, 0, 0);
        }
    }

    if (gn0 < n) {
#pragma unroll
        for (int t = 0; t < 8; ++t) {
            const int cb = (t & 3) * 16 + kq * 4;
            union { _Float16 h[4]; uint2 u; } u;
#pragma unroll
            for (int r = 0; r < 4; ++r) u.h[r] = (_Float16)acc[t][r];
            _Float16* dstp = (t < 4) ? (Y + (size_t)gn * HID + cb)
                                     : (Rh + (size_t)gn * HID + cb);
            *(uint2*)dstp = u.u;
        }
    }
}

// ---------------- aggregation (+ optional fused classifier) ----------------
// Half-wave h2 gathers, 16-edge batches, fp32 accumulate (measured-best form).

__device__ __forceinline__ void acc2(float& ax, float& ay, h2 v) {
    ax += (float)v[0];
    ay += (float)v[1];
}

template <bool CLS>
__global__ __launch_bounds__(256) void k_agg(const _Float16* __restrict__ Y,
                                             const _Float16* __restrict__ Rm,
                                             const float* __restrict__ bias,
                                             const int* __restrict__ rowptr,
                                             const int* __restrict__ col,
                                             _Float16* __restrict__ H,
                                             const float* __restrict__ Wc,
                                             const float* __restrict__ bc,
                                             float* __restrict__ out, int n) {
    const int lane = threadIdx.x & 63;
    const int node = blockIdx.x * 4 + (threadIdx.x >> 6);
    if (node >= n) return;
    const int half_ = lane >> 5;            // which edge of the pair
    const unsigned fp = (unsigned)(lane & 31); // feature-pair index (h2 units)
    const h2* __restrict__ Y2 = (const h2*)Y;
    const int s = rowptr[node], e = rowptr[node + 1];
    float ax0 = 0.f, ay0 = 0.f, ax1 = 0.f, ay1 = 0.f;
    int i = s + half_;
    for (; i + 14 < e; i += 16) {           // 8 edges per half-wave in flight
        int c[8];
#pragma unroll
        for (int j = 0; j < 8; ++j) c[j] = col[i + 2 * j];
        h2 y[8];
#pragma unroll
        for (int j = 0; j < 8; ++j) y[j] = Y2[(unsigned)c[j] * 32u + fp];
#pragma unroll
        for (int j = 0; j < 8; j += 2) {
            acc2(ax0, ay0, y[j]);
            acc2(ax1, ay1, y[j + 1]);
        }
    }
    for (; i + 6 < e; i += 8) {
        int c[4];
#pragma unroll
        for (int j = 0; j < 4; ++j) c[j] = col[i + 2 * j];
        h2 y[4];
#pragma unroll
        for (int j = 0; j < 4; ++j) y[j] = Y2[(unsigned)c[j] * 32u + fp];
        acc2(ax0, ay0, y[0]);
        acc2(ax1, ay1, y[1]);
        acc2(ax0, ay0, y[2]);
        acc2(ax1, ay1, y[3]);
    }
    for (; i < e; i += 2)
        acc2(ax0, ay0, Y2[(unsigned)col[i] * 32u + fp]);
    float ax = ax0 + ax1, ay = ay0 + ay1;
    ax += __shfl_xor(ax, 32, 64);
    ay += __shfl_xor(ay, 32, 64);
    const float vx = __shfl(ax, lane >> 1, 64);
    const float vy = __shfl(ay, lane >> 1, 64);
    const float acc = (lane & 1) ? vy : vx;
    const int deg = e - s;
    float h = acc / (float)(deg > 1 ? deg : 1) + bias[lane] +
              (float)Rm[(size_t)node * HID + lane];
    h = fmaxf(h, 0.f);
    if (!CLS) {
        H[(size_t)node * HID + lane] = (_Float16)h;
    } else {
        float p0 = h * Wc[lane * 2 + 0];
        float p1 = h * Wc[lane * 2 + 1];
#pragma unroll
        for (int off = 32; off > 0; off >>= 1) {
            p0 += __shfl_xor(p0, off, 64);
            p1 += __shfl_xor(p1, off, 64);
        }
        if (lane == 0) {
            out[(size_t)node * 2 + 0] = p0 + bc[0];
            out[(size_t)node * 2 + 1] = p1 + bc[1];
        }
    }
}

// ---------------- launch ----------------

extern "C" void kernel_launch(void* const* d_in, const int* in_sizes, int n_in,
                              void* d_out, int out_size, void* d_ws, size_t ws_size,
                              hipStream_t stream) {
    const float* x   = (const float*)d_in[0];
    const int*   ei  = (const int*)d_in[1];
    const float* W1l = (const float*)d_in[2];
    const float* b1  = (const float*)d_in[3];
    const float* W1r = (const float*)d_in[4];
    const float* W2l = (const float*)d_in[5];
    const float* b2  = (const float*)d_in[6];
    const float* W2r = (const float*)d_in[7];
    const float* Wc  = (const float*)d_in[8];
    const float* bc  = (const float*)d_in[9];
    float* out = (float*)d_out;
    const int* src = ei;
    const int* dst = ei + NE;

    char* base = (char*)d_ws;
    size_t off = 0;
    auto alloc = [&](size_t bytes) {
        void* p = base + off;
        off = (off + bytes + 255) & ~(size_t)255;
        return p;
    };
    int*      bcnt    = (int*)alloc((size_t)NBUK * 4);
    int*      bbase   = (int*)alloc((size_t)(NBUK + 1) * 4);
    int*      rowptr  = (int*)alloc((size_t)(NN + 1) * 4);
    int*      col     = (int*)alloc((size_t)NE * 4);
    // Eb (8.8 MB) is dead after k_csrb -> alias it under Y (fp16, 12.8 MB)
    _Float16* Y       = (_Float16*)alloc((size_t)NN * HID * 2 + 256);
    _Float16* Rh      = (_Float16*)alloc((size_t)NN * HID * 2);
    _Float16* Hh      = (_Float16*)alloc((size_t)NN * HID * 2);
    _Float16* Wt1     = (_Float16*)alloc((size_t)128 * KP1 * 2);
    _Float16* Wt2     = (_Float16*)alloc((size_t)128 * KP2 * 2);
    unsigned* Eb      = (unsigned*)Y;

    const int sb = (NE + SC_CHUNK - 1) / SC_CHUNK; // 196
    const int wb = (128 * KP1 + 128 * KP2 + 255) / 256; // 128

    hipMemsetAsync(bcnt, 0, (size_t)NBUK * 4, stream);
    k_scatter<<<sb, 256, 0, stream>>>(src, dst, bcnt, Eb, NE);
    k_bscan<<<1, 256, 0, stream>>>(bcnt, bbase);
    k_csrb<<<NBUK, 256, 0, stream>>>(Eb, bbase, rowptr, col, NN);
    k_wcvt<<<wb, 256, 0, stream>>>(W1l, W1r, W2l, W2r, Wt1, Wt2);

    k_lin1<<<(NN + 63) / 64, 256, 0, stream>>>(x, Wt1, Y, Rh, NN);
    k_agg<false><<<(NN + 3) / 4, 256, 0, stream>>>(Y, Rh, b1, rowptr, col, Hh,
                                                   nullptr, nullptr, nullptr, NN);
    k_linear<KP2><<<(NN + 63) / 64, 256, 0, stream>>>(Hh, Wt2, Y, Rh, NN);
    k_agg<true><<<(NN + 3) / 4, 256, 0, stream>>>(Y, Rh, b2, rowptr, col, nullptr,
                                                  Wc, bc, out, NN);
}